// Round 13
// baseline (180.473 us; speedup 1.0000x reference)
//
#include <hip/hip_runtime.h>

// Graph message passing: out = nf + mean_{e: tgt(e)=v}(nf[src(e)] + nf[v]), residual.
// dest-term telescopes: out[v] = nf[v]*(cnt>0?2:1) + (sum nf[src]) / max(cnt,1)
//
// R3 400us atomics -> R4 342 CSR -> R9 214 count-sort+VGPR -> R10 193 ->
// R11 170 (padded buckets; agg 63.8us stable). R11 residue: place writes runs
// of 2 entries/(block,bucket) -> line fragmentation. R12: two-level. Place into
// 196 coarse buckets (runs of ~32 = full lines, detect fused). Aggregate: 3125
// fine WGs ballot-filter their 32-node window from the coarse bucket (L2-
// resident, XCD-swizzled so siblings share an L2) then R11's sort+VGPR gather.

#define D 64
#define CSHIFT 9               // coarse bucket = t >> 9  (512 nodes)
#define CNODES 512
#define FSHIFT 5               // fine window = 32 nodes
#define FNODES 32
#define SRC_BITS 17            // pack = (tlocal << 17) | src ; needs N <= 131072
#define CAPC 9216              // coarse capacity (mean 8192, sigma 90 -> +11s)
#define CAPF 768               // fine matched capacity (mean 512, sigma 23 -> +11s)
#define K_BLOCKS 256
#define K_THREADS 512

// ---------- helpers ----------

__global__ void detect_idx_width(const int* __restrict__ ei, int* __restrict__ flag) {
    unsigned long long nz = __ballot(ei[2 * (int)threadIdx.x + 1] != 0);
    if (threadIdx.x == 0) *flag = (nz == 0ULL) ? 1 : 0;
}

__device__ __forceinline__ int load_src(const int* ei, int e, int n_edges, bool is64) {
    return is64 ? ei[2 * (size_t)e] : ei[e];
}
__device__ __forceinline__ int load_tgt(const int* ei, int e, int n_edges, bool is64) {
    return is64 ? ei[2 * ((size_t)n_edges + e)] : ei[(size_t)n_edges + e];
}

// ---------- K1: place edges into padded COARSE buckets (fused detect) ----------

__global__ __launch_bounds__(K_THREADS) void place_coarse(
        const int* __restrict__ ei, int* __restrict__ gcnt,
        int* __restrict__ bucket, int n_edges, int ncoarse) {
    __shared__ int lhist[256], lbase[256], lcur[256];   // ncoarse <= 256
    __shared__ int is64_sh;
    const int tid = threadIdx.x;
    if (tid < 64) {                                     // fused dtype detect
        unsigned long long nz = __ballot(ei[2 * tid + 1] != 0);
        if (tid == 0) is64_sh = (nz == 0ULL) ? 1 : 0;
    }
    for (int i = tid; i < ncoarse; i += blockDim.x) { lhist[i] = 0; lcur[i] = 0; }
    __syncthreads();
    const bool is64 = (is64_sh != 0);
    const int epb = (n_edges + gridDim.x - 1) / gridDim.x;
    const int e0 = blockIdx.x * epb;
    const int e1 = min(n_edges, e0 + epb);

    for (int e = e0 + tid; e < e1; e += blockDim.x)
        atomicAdd(&lhist[load_tgt(ei, e, n_edges, is64) >> CSHIFT], 1);
    __syncthreads();
    for (int b = tid; b < ncoarse; b += blockDim.x) {
        int c = lhist[b];
        lbase[b] = c ? (b * CAPC + atomicAdd(&gcnt[b], c)) : 0;   // reserve run ~32
    }
    __syncthreads();
    for (int e = e0 + tid; e < e1; e += blockDim.x) {
        int s = load_src(ei, e, n_edges, is64);
        int t = load_tgt(ei, e, n_edges, is64);
        int b = t >> CSHIFT;
        int pos = lbase[b] + atomicAdd(&lcur[b], 1);    // LDS cursor
        if (pos < (b + 1) * CAPC)                       // clamp: memory-safe overflow
            bucket[pos] = ((t & (CNODES - 1)) << SRC_BITS) | s;
    }
}

// ---------- K2: fine aggregate: ballot-filter window + count-sort + VGPR gather ----------

__global__ __launch_bounds__(256) void bucket_aggregate(
        const float* __restrict__ nf, const int* __restrict__ gcnt,
        const int* __restrict__ bucket, float* __restrict__ out,
        int n_nodes, int nfine) {
    __shared__ int stq[CAPF];                           // filtered entries
    __shared__ int srt[CAPF];                           // count-sorted src ids
    __shared__ int bins[FNODES], ofs[FNODES], cur[FNODES];
    __shared__ int mcnt_sh;
    const int tid = threadIdx.x;
    const int wid = tid >> 6;
    const int lane = tid & 63;
    const int SMASK = (1 << SRC_BITS) - 1;

    // bijective XCD swizzle: contiguous work chunk per XCD so the 16 sibling
    // WGs of one coarse bucket share an L2 (bid%8 ~ XCD round-robin).
    const int bid = blockIdx.x;
    const int q = nfine >> 3, r8 = nfine & 7;
    const int xcd = bid & 7, rank = bid >> 3;
    const int w = (xcd < r8 ? xcd * (q + 1) : r8 * (q + 1) + (xcd - r8) * q) + rank;

    const int c = w >> 4;                               // coarse bucket
    const int sub = w & 15;                             // 32-node window within it
    const int base = w * FNODES;

    float acc[8];
    int cnt[8];
#pragma unroll
    for (int k = 0; k < 8; ++k) { acc[k] = 0.f; cnt[k] = 0; }

    if (tid == 0) mcnt_sh = 0;
    if (tid < FNODES) bins[tid] = 0;
    __syncthreads();

    // ---- filter-compact my window's entries (ballot + one LDS atomic/wave) ----
    const int m = min(gcnt[c], CAPC);
    const size_t c0 = (size_t)c * CAPC;
    for (int i = tid; i < m; i += 256) {
        int p = bucket[c0 + i];
        int tl = p >> SRC_BITS;
        bool match = ((tl >> FSHIFT) == sub);
        unsigned long long mk = __ballot(match);
        int wbase = 0;
        if (lane == 0) wbase = atomicAdd(&mcnt_sh, (int)__popcll(mk));
        wbase = __shfl(wbase, 0, 64);
        if (match) {
            int pos = wbase + (int)__popcll(mk & ((1ULL << lane) - 1ULL));
            if (pos < CAPF)
                stq[pos] = ((tl & (FNODES - 1)) << SRC_BITS) | (p & SMASK);
        }
    }
    __syncthreads();
    const int mm = min(mcnt_sh, CAPF);

    // ---- count-sort by local node (32 bins) ----
    for (int i = tid; i < mm; i += 256) atomicAdd(&bins[stq[i] >> SRC_BITS], 1);
    __syncthreads();
    if (tid < FNODES) {                                 // 32-wide shfl scan
        int v = bins[tid];
        int incl = v;
#pragma unroll
        for (int off = 1; off < FNODES; off <<= 1) {
            int up = __shfl_up(incl, off, FNODES);
            if (tid >= off) incl += up;
        }
        ofs[tid] = incl - v;
        cur[tid] = incl - v;
    }
    __syncthreads();
    for (int i = tid; i < mm; i += 256) {
        int p = stq[i];
        int pos = atomicAdd(&cur[p >> SRC_BITS], 1);
        srt[pos] = p & SMASK;
    }
    __syncthreads();

    // ---- gather: wave wid owns nodes r = wid*8+k (static acc, rule #20) ----
#pragma unroll
    for (int k = 0; k < 8; ++k) {
        int r = (wid << 3) + k;
        int j0 = ofs[r];
        int n = bins[r];
        int j1 = j0 + n;
        cnt[k] += n;
        int j = j0;
        for (; j + 8 <= j1; j += 8) {                   // 8-deep gather MLP
            int a0 = srt[j],     a1 = srt[j + 1], a2 = srt[j + 2], a3 = srt[j + 3];
            int a4 = srt[j + 4], a5 = srt[j + 5], a6 = srt[j + 6], a7 = srt[j + 7];
            float v0 = nf[(size_t)a0 * D + lane];
            float v1 = nf[(size_t)a1 * D + lane];
            float v2 = nf[(size_t)a2 * D + lane];
            float v3 = nf[(size_t)a3 * D + lane];
            float v4 = nf[(size_t)a4 * D + lane];
            float v5 = nf[(size_t)a5 * D + lane];
            float v6 = nf[(size_t)a6 * D + lane];
            float v7 = nf[(size_t)a7 * D + lane];
            acc[k] += v0; acc[k] += v1; acc[k] += v2; acc[k] += v3;
            acc[k] += v4; acc[k] += v5; acc[k] += v6; acc[k] += v7;
        }
        for (; j + 4 <= j1; j += 4) {
            int a0 = srt[j], a1 = srt[j + 1], a2 = srt[j + 2], a3 = srt[j + 3];
            float v0 = nf[(size_t)a0 * D + lane];
            float v1 = nf[(size_t)a1 * D + lane];
            float v2 = nf[(size_t)a2 * D + lane];
            float v3 = nf[(size_t)a3 * D + lane];
            acc[k] += v0; acc[k] += v1; acc[k] += v2; acc[k] += v3;
        }
        for (; j < j1; ++j) acc[k] += nf[(size_t)srt[j] * D + lane];
    }

    // ---- fused mean + residual epilogue ----
#pragma unroll
    for (int k = 0; k < 8; ++k) {
        int node = base + (wid << 3) + k;
        if (node < n_nodes) {
            float cc = (float)cnt[k];
            float self = nf[(size_t)node * D + lane];
            float scale = (cc > 0.f) ? 2.0f : 1.0f;
            float inv = (cc > 0.f) ? (1.0f / cc) : 1.0f;
            out[(size_t)node * D + lane] = self * scale + acc[k] * inv;
        }
    }
}

// ---------- fallback atomic path (R3, known-correct; used only if ws too small) ----------

__global__ __launch_bounds__(256) void edge_scatter(
        const float* __restrict__ nf, const int* __restrict__ ei,
        const int* __restrict__ flag, float* __restrict__ agg,
        int* __restrict__ cnt, int n_edges) {
    const bool is64 = (*flag != 0);
    const int lane = threadIdx.x & 63;
    const int wave = (int)((blockIdx.x * (unsigned)blockDim.x + threadIdx.x) >> 6);
    const int nwaves = (int)((gridDim.x * (unsigned)blockDim.x) >> 6);
    for (int e = wave; e < n_edges; e += nwaves) {
        int s = load_src(ei, e, n_edges, is64);
        int t = load_tgt(ei, e, n_edges, is64);
        atomicAdd(&agg[(size_t)t * D + lane], nf[(size_t)s * D + lane]);
        if (lane == 0) atomicAdd(&cnt[t], 1);
    }
}

__global__ __launch_bounds__(256) void finalize(
        const float* __restrict__ nf, const int* __restrict__ cnt,
        float* __restrict__ out, int n_elems) {
    int i = blockIdx.x * blockDim.x + threadIdx.x;
    if (i >= n_elems) return;
    int v = i >> 6;
    float c = (float)cnt[v];
    float inv = (c > 0.f) ? (1.0f / c) : 1.0f;
    float scale = (c > 0.f) ? 2.0f : 1.0f;
    out[i] = nf[i] * scale + out[i] * inv;
}

// ---------- launch ----------

extern "C" void kernel_launch(void* const* d_in, const int* in_sizes, int n_in,
                              void* d_out, int out_size, void* d_ws, size_t ws_size,
                              hipStream_t stream) {
    const float* nf = (const float*)d_in[0];
    const int* ei = (const int*)d_in[1];
    float* out = (float*)d_out;

    const int n_nodes = in_sizes[0] / D;      // 100000
    const int n_edges = in_sizes[1] / 2;      // 1600000

    const int ncoarse = (n_nodes + CNODES - 1) / CNODES;   // 196
    const int nfine   = (n_nodes + FNODES - 1) / FNODES;   // 3125

    // ws layout (ints): gcnt[ncoarse] | flag[1] | bucket[ncoarse*CAPC]
    int* gcnt   = (int*)d_ws;
    int* flag   = gcnt + ncoarse;
    int* bucket = flag + 1;
    const size_t need = ((size_t)ncoarse * CAPC + ncoarse + 1) * sizeof(int); // ~7.2MB

    if (ws_size >= need && n_nodes <= (1 << SRC_BITS) && ncoarse <= 256) {
        hipMemsetAsync(gcnt, 0, (size_t)ncoarse * sizeof(int), stream);
        place_coarse<<<K_BLOCKS, K_THREADS, 0, stream>>>(
            ei, gcnt, bucket, n_edges, ncoarse);
        bucket_aggregate<<<nfine, 256, 0, stream>>>(
            nf, gcnt, bucket, out, n_nodes, nfine);
    } else {
        // Fallback: R3 atomic path.
        hipMemsetAsync(d_out, 0, (size_t)out_size * sizeof(float), stream);
        hipMemsetAsync(d_ws, 0, ((size_t)n_nodes + 1) * sizeof(int), stream);
        int* fcnt = (int*)d_ws;
        int* fflag = fcnt + n_nodes;
        detect_idx_width<<<1, 64, 0, stream>>>(ei, fflag);
        edge_scatter<<<2048, 256, 0, stream>>>(nf, ei, fflag, out, fcnt, n_edges);
        finalize<<<(n_nodes * D + 255) / 256, 256, 0, stream>>>(nf, fcnt, out, n_nodes * D);
    }
}

// Round 15
// 166.425 us; speedup vs baseline: 1.0844x; 1.0844x over previous
//
#include <hip/hip_runtime.h>

// Graph message passing: out = nf + mean_{e: tgt(e)=v}(nf[src(e)] + nf[v]), residual.
// dest-term telescopes: out[v] = nf[v]*(cnt>0?2:1) + (sum nf[src]) / max(cnt,1)
//
// R11 170us: agg 63.8 (proven), place ~80. R13 ruled OUT write-fragmentation
// (full-line runs, same ~80us) and ruled OUT coarse-filter aggregate (90us,
// reverted). R14: place at 3x occupancy (1024thr, 25KB LDS via hist-as-cursor,
// 391 blocks = 6256 waves), single edge read (4-entry register stash, static-
// indexed per rule #20), detect fused. Aggregate = R11 byte-equivalent.

#define D 64
#define NPB 32                 // nodes per bucket (bkt = t >> 5)
#define NPB_SHIFT 5
#define SRC_BITS 17            // pack = (tlocal << 17) | src ; needs N <= 131072
#define CAP 768                // bucket capacity (mean 512, sigma 22.6, +11s)
#define CHUNK 1024             // aggregate: staged entries per sort pass
#define EPB 4096               // edges per place block (4 per thread)
#define P_THREADS 1024

// ---------- helpers ----------

__global__ void detect_idx_width(const int* __restrict__ ei, int* __restrict__ flag) {
    unsigned long long nz = __ballot(ei[2 * (int)threadIdx.x + 1] != 0);
    if (threadIdx.x == 0) *flag = (nz == 0ULL) ? 1 : 0;
}

__device__ __forceinline__ int load_src(const int* ei, int e, int n_edges, bool is64) {
    return is64 ? ei[2 * (size_t)e] : ei[e];
}
__device__ __forceinline__ int load_tgt(const int* ei, int e, int n_edges, bool is64) {
    return is64 ? ei[2 * ((size_t)n_edges + e)] : ei[(size_t)n_edges + e];
}

// ---------- K1: place with register stash (single edge read, fused detect) ----------
// LDS: lh[nb] (hist -> reused as cursor) + lbase[nb] = 25KB @ nb=3125.

__global__ __launch_bounds__(P_THREADS) void place_stash(
        const int* __restrict__ ei, int* __restrict__ gcnt,
        int* __restrict__ bucket, int n_edges, int nb) {
    extern __shared__ int sh[];
    int* lh    = sh;            // [nb] histogram, then write cursor
    int* lbase = sh + nb;       // [nb] reserved base
    __shared__ int is64_sh;
    const int tid = threadIdx.x;

    if (tid < 64) {                                     // fused dtype detect
        unsigned long long nz = __ballot(ei[2 * tid + 1] != 0);
        if (tid == 0) is64_sh = (nz == 0ULL) ? 1 : 0;
    }
    for (int i = tid; i < nb; i += P_THREADS) lh[i] = 0;
    __syncthreads();
    const bool is64 = (is64_sh != 0);
    const int e0 = blockIdx.x * EPB;
    const int e1 = min(n_edges, e0 + EPB);

    // pass 1: read once, stash packed entry + bucket in static-indexed regs
    int pk0 = 0, pk1 = 0, pk2 = 0, pk3 = 0;
    int bk0 = -1, bk1 = -1, bk2 = -1, bk3 = -1;
    {
        int e = e0 + tid;
        if (e < e1) {
            int s = load_src(ei, e, n_edges, is64);
            int t = load_tgt(ei, e, n_edges, is64);
            bk0 = t >> NPB_SHIFT;
            pk0 = ((t & (NPB - 1)) << SRC_BITS) | s;
            atomicAdd(&lh[bk0], 1);
        }
        e += P_THREADS;
        if (e < e1) {
            int s = load_src(ei, e, n_edges, is64);
            int t = load_tgt(ei, e, n_edges, is64);
            bk1 = t >> NPB_SHIFT;
            pk1 = ((t & (NPB - 1)) << SRC_BITS) | s;
            atomicAdd(&lh[bk1], 1);
        }
        e += P_THREADS;
        if (e < e1) {
            int s = load_src(ei, e, n_edges, is64);
            int t = load_tgt(ei, e, n_edges, is64);
            bk2 = t >> NPB_SHIFT;
            pk2 = ((t & (NPB - 1)) << SRC_BITS) | s;
            atomicAdd(&lh[bk2], 1);
        }
        e += P_THREADS;
        if (e < e1) {
            int s = load_src(ei, e, n_edges, is64);
            int t = load_tgt(ei, e, n_edges, is64);
            bk3 = t >> NPB_SHIFT;
            pk3 = ((t & (NPB - 1)) << SRC_BITS) | s;
            atomicAdd(&lh[bk3], 1);
        }
    }
    __syncthreads();
    // reserve contiguous runs; reset lh to serve as write cursor
    for (int b = tid; b < nb; b += P_THREADS) {
        int c = lh[b];
        lbase[b] = c ? (b * CAP + atomicAdd(&gcnt[b], c)) : 0;
        lh[b] = 0;
    }
    __syncthreads();
    // pass 2: write from registers (no second edge read)
    if (bk0 >= 0) {
        int pos = lbase[bk0] + atomicAdd(&lh[bk0], 1);
        if (pos < (bk0 + 1) * CAP) bucket[pos] = pk0;
    }
    if (bk1 >= 0) {
        int pos = lbase[bk1] + atomicAdd(&lh[bk1], 1);
        if (pos < (bk1 + 1) * CAP) bucket[pos] = pk1;
    }
    if (bk2 >= 0) {
        int pos = lbase[bk2] + atomicAdd(&lh[bk2], 1);
        if (pos < (bk2 + 1) * CAP) bucket[pos] = pk2;
    }
    if (bk3 >= 0) {
        int pos = lbase[bk3] + atomicAdd(&lh[bk3], 1);
        if (pos < (bk3 + 1) * CAP) bucket[pos] = pk3;
    }
}

// ---------- K2: per-bucket count-sort in LDS + VGPR accumulation (R11 proven) ----------

__global__ __launch_bounds__(256) void bucket_aggregate(
        const float* __restrict__ nf, const int* __restrict__ gcnt,
        const int* __restrict__ bucket, float* __restrict__ out, int n_nodes) {
    __shared__ int st[CHUNK];                         // staged raw entries
    __shared__ int srt[CHUNK];                        // count-sorted src ids
    __shared__ int bins[NPB], ofs[NPB], cur[NPB];
    const int blk = blockIdx.x;
    const int base = blk * NPB;
    const int tid = threadIdx.x;
    const int wid = tid >> 6;
    const int lane = tid & 63;
    const int SMASK = (1 << SRC_BITS) - 1;

    float acc[8];
    int cnt[8];
#pragma unroll
    for (int k = 0; k < 8; ++k) { acc[k] = 0.f; cnt[k] = 0; }

    const int s0 = blk * CAP;
    const int m = min(gcnt[blk], CAP);

    for (int done = 0; done < m; done += CHUNK) {
        const int mc = min(CHUNK, m - done);
        if (tid < NPB) bins[tid] = 0;
        __syncthreads();
        for (int i = tid; i < mc; i += 256) {
            int p = bucket[s0 + done + i];
            st[i] = p;
            atomicAdd(&bins[p >> SRC_BITS], 1);
        }
        __syncthreads();
        if (tid < NPB) {                              // 32-wide shfl scan
            int v = bins[tid];
            int incl = v;
#pragma unroll
            for (int off = 1; off < NPB; off <<= 1) {
                int up = __shfl_up(incl, off, NPB);
                if (tid >= off) incl += up;
            }
            ofs[tid] = incl - v;
            cur[tid] = incl - v;
        }
        __syncthreads();
        for (int i = tid; i < mc; i += 256) {
            int p = st[i];
            int pos = atomicAdd(&cur[p >> SRC_BITS], 1);
            srt[pos] = p & SMASK;
        }
        __syncthreads();
#pragma unroll
        for (int k = 0; k < 8; ++k) {
            int r = (wid << 3) + k;
            int j0 = ofs[r];
            int n = bins[r];
            int j1 = j0 + n;
            cnt[k] += n;
            int j = j0;
            for (; j + 8 <= j1; j += 8) {             // 8-deep gather MLP
                int a0 = srt[j],     a1 = srt[j + 1], a2 = srt[j + 2], a3 = srt[j + 3];
                int a4 = srt[j + 4], a5 = srt[j + 5], a6 = srt[j + 6], a7 = srt[j + 7];
                float v0 = nf[(size_t)a0 * D + lane];
                float v1 = nf[(size_t)a1 * D + lane];
                float v2 = nf[(size_t)a2 * D + lane];
                float v3 = nf[(size_t)a3 * D + lane];
                float v4 = nf[(size_t)a4 * D + lane];
                float v5 = nf[(size_t)a5 * D + lane];
                float v6 = nf[(size_t)a6 * D + lane];
                float v7 = nf[(size_t)a7 * D + lane];
                acc[k] += v0; acc[k] += v1; acc[k] += v2; acc[k] += v3;
                acc[k] += v4; acc[k] += v5; acc[k] += v6; acc[k] += v7;
            }
            for (; j + 4 <= j1; j += 4) {
                int a0 = srt[j], a1 = srt[j + 1], a2 = srt[j + 2], a3 = srt[j + 3];
                float v0 = nf[(size_t)a0 * D + lane];
                float v1 = nf[(size_t)a1 * D + lane];
                float v2 = nf[(size_t)a2 * D + lane];
                float v3 = nf[(size_t)a3 * D + lane];
                acc[k] += v0; acc[k] += v1; acc[k] += v2; acc[k] += v3;
            }
            for (; j < j1; ++j) acc[k] += nf[(size_t)srt[j] * D + lane];
        }
        __syncthreads();                              // before st/bins reuse
    }

#pragma unroll
    for (int k = 0; k < 8; ++k) {
        int node = base + (wid << 3) + k;
        if (node < n_nodes) {
            float c = (float)cnt[k];
            float self = nf[(size_t)node * D + lane];
            float scale = (c > 0.f) ? 2.0f : 1.0f;
            float inv = (c > 0.f) ? (1.0f / c) : 1.0f;
            out[(size_t)node * D + lane] = self * scale + acc[k] * inv;
        }
    }
}

// ---------- fallback atomic path (R3, known-correct; used only if ws too small) ----------

__global__ __launch_bounds__(256) void edge_scatter(
        const float* __restrict__ nf, const int* __restrict__ ei,
        const int* __restrict__ flag, float* __restrict__ agg,
        int* __restrict__ cnt, int n_edges) {
    const bool is64 = (*flag != 0);
    const int lane = threadIdx.x & 63;
    const int wave = (int)((blockIdx.x * (unsigned)blockDim.x + threadIdx.x) >> 6);
    const int nwaves = (int)((gridDim.x * (unsigned)blockDim.x) >> 6);
    for (int e = wave; e < n_edges; e += nwaves) {
        int s = load_src(ei, e, n_edges, is64);
        int t = load_tgt(ei, e, n_edges, is64);
        atomicAdd(&agg[(size_t)t * D + lane], nf[(size_t)s * D + lane]);
        if (lane == 0) atomicAdd(&cnt[t], 1);
    }
}

__global__ __launch_bounds__(256) void finalize(
        const float* __restrict__ nf, const int* __restrict__ cnt,
        float* __restrict__ out, int n_elems) {
    int i = blockIdx.x * blockDim.x + threadIdx.x;
    if (i >= n_elems) return;
    int v = i >> 6;
    float c = (float)cnt[v];
    float inv = (c > 0.f) ? (1.0f / c) : 1.0f;
    float scale = (c > 0.f) ? 2.0f : 1.0f;
    out[i] = nf[i] * scale + out[i] * inv;
}

// ---------- launch ----------

extern "C" void kernel_launch(void* const* d_in, const int* in_sizes, int n_in,
                              void* d_out, int out_size, void* d_ws, size_t ws_size,
                              hipStream_t stream) {
    const float* nf = (const float*)d_in[0];
    const int* ei = (const int*)d_in[1];
    float* out = (float*)d_out;

    const int n_nodes = in_sizes[0] / D;      // 100000
    const int n_edges = in_sizes[1] / 2;      // 1600000

    const int nb = (n_nodes + NPB - 1) / NPB; // 3125

    // ws layout (ints): gcnt[nb] | flag[1] | bucket[nb*CAP]
    int* gcnt   = (int*)d_ws;
    int* flag   = gcnt + nb;
    int* bucket = flag + 1;
    const size_t need = ((size_t)nb * CAP + nb + 1) * sizeof(int);   // ~9.6 MB
    const size_t place_lds = (size_t)2 * nb * sizeof(int);           // 25 KB

    if (ws_size >= need && n_nodes <= (1 << SRC_BITS) && place_lds <= 64 * 1024) {
        hipMemsetAsync(gcnt, 0, (size_t)nb * sizeof(int), stream);
        const int nblk = (n_edges + EPB - 1) / EPB;                  // 391
        place_stash<<<nblk, P_THREADS, place_lds, stream>>>(
            ei, gcnt, bucket, n_edges, nb);
        bucket_aggregate<<<nb, 256, 0, stream>>>(nf, gcnt, bucket, out, n_nodes);
    } else {
        // Fallback: R3 atomic path.
        hipMemsetAsync(d_out, 0, (size_t)out_size * sizeof(float), stream);
        hipMemsetAsync(d_ws, 0, ((size_t)n_nodes + 1) * sizeof(int), stream);
        int* fcnt = (int*)d_ws;
        int* fflag = fcnt + n_nodes;
        detect_idx_width<<<1, 64, 0, stream>>>(ei, fflag);
        edge_scatter<<<2048, 256, 0, stream>>>(nf, ei, fflag, out, fcnt, n_edges);
        finalize<<<(n_nodes * D + 255) / 256, 256, 0, stream>>>(nf, fcnt, out, n_nodes * D);
    }
}